// Round 15
// baseline (60.298 us; speedup 1.0000x reference)
//
#include <hip/hip_runtime.h>
#include <hip/hip_bf16.h>

typedef __hip_bfloat16 bf16;
typedef unsigned int uint32;
typedef __attribute__((ext_vector_type(8))) short bf16x8;
typedef __attribute__((ext_vector_type(4))) float f32x4;

#define BB 2
#define NN 2048
#define CENTER 15.0f

// workspace float offsets (end = 4,378,640 f32 = 17.5 MB; ws >= 268 MB)
#define QT_OFF   16u       // u32 view [8 bh][2048 i][48]  (96 bf16 slots)
#define KT_OFF   786448u   // u32 view [8 bh][2048 j][48]
#define VT_OFF   1572880u  // u16 view [8 bh][28 d][2048 j]
#define CQ_OFF   1802256u  // f32 [4096]         |c-15|^2
#define SB_OFF   1806352u  // f32 [8 bh][2048]   -0.5*wc*|kp_c|^2
#define PAR_OFF  2281488u  // f32 [8 bh][8 jc][2048][16]

__device__ __forceinline__ float b2f(bf16 x) { return __bfloat162float(x); }

__device__ __forceinline__ float ldm(const void* p, size_t i, int mode) {
  return mode ? ((const float*)p)[i] : b2f(((const bf16*)p)[i]);
}

__device__ __forceinline__ float softplus_f(float x) {
  return (x > 20.f) ? x : log1pf(__expf(x));
}

__device__ __forceinline__ unsigned pk2(float a, float b) {
  union { __hip_bfloat162 v; unsigned u; } cv;
  cv.v.x = __float2bfloat16(a); cv.v.y = __float2bfloat16(b);
  return cv.u;
}
__device__ __forceinline__ float2 upk2(unsigned u) {
  union { unsigned u; __hip_bfloat162 v; } cv; cv.u = u;
  return make_float2(__bfloat162float(cv.v.x), __bfloat162float(cv.v.y));
}
__device__ __forceinline__ unsigned short f2bu(float x) {
  union { bf16 b; unsigned short u; } c; c.b = __float2bfloat16(x); return c.u;
}
__device__ __forceinline__ float lo_part(float x) {
  return x - __bfloat162float(__float2bfloat16(x));
}

// MFMA table slot builders (proven rounds 11-14).
__device__ float qslot(int h, int s, const float* spro, const float* cc,
                       float wl, float wc) {
  if (s < 16) return wl * spro[h * 16 + s];
  if (s < 28) return wc * spro[192 + h * 12 + (s - 16)];
  if (s < 32) return 0.f;
  if (s < 44) return wc * spro[192 + h * 12 + (s - 32)];
  if (s < 56) return lo_part(wc * spro[192 + h * 12 + (s - 44)]);
  if (s < 64) return 0.f;
  if (s < 67) return cc[s - 64];
  if (s < 70) return cc[s - 67];
  if (s < 73) return lo_part(cc[s - 70]);
  return 0.f;
}
__device__ float kslot(int h, int s, const float* spro, const float* cc) {
  if (s < 16) return spro[64 + h * 16 + s];
  if (s < 28) return spro[240 + h * 12 + (s - 16)];
  if (s < 32) return 0.f;
  if (s < 44) return lo_part(spro[240 + h * 12 + (s - 32)]);
  if (s < 56) return spro[240 + h * 12 + (s - 44)];
  if (s < 64) return 0.f;
  if (s < 67) return cc[s - 64];
  if (s < 70) return lo_part(cc[s - 67]);
  if (s < 73) return cc[s - 70];
  return 0.f;
}

// ---------------------------------------------------------------------------
// Kernel A: projections + MFMA table packing (verbatim from passing round 14).
// 4 rows/block (grid 1024 x 512); in-block dtype detect.
// ---------------------------------------------------------------------------
__global__ __launch_bounds__(512) void proj_kernel(
    const void* feat, const void* coords,
    const void* Wq,  const void* bq,  const void* Wk,  const void* bk,
    const void* Wv,  const void* bv,  const void* Wqp, const void* bqp,
    const void* Wkp, const void* bkp, const void* Wvp, const void* bvp,
    const void* w_c, const void* w_l, float* ws)
{
  const int t = threadIdx.x;
  const int row0 = blockIdx.x * 4;
  const int b = row0 >> 11;
  __shared__ int scnt;
  __shared__ float sfT[64 * 4];       // [f][rr]
  __shared__ float spro[4][336];

  if (t == 0) scnt = 0;
  __syncthreads();
  {
    const unsigned short uv = ((const unsigned short*)feat)[t];
    const unsigned e = (uv >> 7) & 0xFFu;
    const unsigned long long bl = __ballot(e >= 0xC0u);
    if ((t & 63) == 0) atomicAdd(&scnt, (int)__popcll(bl));
  }
  __syncthreads();
  const int mode = (scnt > 16) ? 1 : 0;

  if (t < 256) {
    const int rr = t >> 6, f = t & 63;
    sfT[f * 4 + rr] = ldm(feat, (size_t)(row0 + rr) * 64 + f, mode);
  }
  __syncthreads();

  if (t < 336) {
    const void *W, *bias; int odim, c, cls, ofs;
    if (t < 64)       { W = Wq;  bias = bq;  odim = 64; c = t;       cls = 0; ofs = 0; }
    else if (t < 128) { W = Wk;  bias = bk;  odim = 64; c = t - 64;  cls = 1; ofs = 64; }
    else if (t < 192) { W = Wv;  bias = bv;  odim = 64; c = t - 128; cls = 2; ofs = 128; }
    else if (t < 240) { W = Wqp; bias = bqp; odim = 48; c = t - 192; cls = 3; ofs = 192; }
    else if (t < 288) { W = Wkp; bias = bkp; odim = 48; c = t - 240; cls = 4; ofs = 240; }
    else              { W = Wvp; bias = bvp; odim = 48; c = t - 288; cls = 5; ofs = 288; }
    const float bb = ldm(bias, c, mode);
    float a0 = bb, a1 = bb, a2 = bb, a3 = bb;
    if (mode) {
      const float* Wf = (const float*)W;
      #pragma unroll 8
      for (int f = 0; f < 64; ++f) {
        const float wf = Wf[(size_t)f * odim + c];
        const float4 fv = *(const float4*)(sfT + f * 4);
        a0 = fmaf(fv.x, wf, a0); a1 = fmaf(fv.y, wf, a1);
        a2 = fmaf(fv.z, wf, a2); a3 = fmaf(fv.w, wf, a3);
      }
    } else {
      const bf16* Wb = (const bf16*)W;
      #pragma unroll 8
      for (int f = 0; f < 64; ++f) {
        const float wf = b2f(Wb[(size_t)f * odim + c]);
        const float4 fv = *(const float4*)(sfT + f * 4);
        a0 = fmaf(fv.x, wf, a0); a1 = fmaf(fv.y, wf, a1);
        a2 = fmaf(fv.z, wf, a2); a3 = fmaf(fv.w, wf, a3);
      }
    }
    float av[4] = {a0, a1, a2, a3};
    #pragma unroll
    for (int rr = 0; rr < 4; ++rr) {
      float acc = av[rr];
      if (cls >= 3) {
        acc += ldm(coords, (size_t)(row0 + rr) * 3 + (c % 3), mode);
        if (cls == 3 || cls == 4) acc -= CENTER;   // center qp,kp (shift-inv)
      }
      spro[rr][ofs + c] = acc;
    }
  }
  __syncthreads();

  if (t < 384) {
    const bool isq = (t < 192);
    const int per = isq ? t : t - 192;
    const int h = per / 48, w = per - h * 48;
    const float wl = softplus_f(ldm(w_l, h, mode)) * 0.25f;
    const float wc = softplus_f(ldm(w_c, h, mode));
    uint32* tab = (uint32*)(ws + (isq ? QT_OFF : KT_OFF));
    #pragma unroll 1
    for (int rr = 0; rr < 4; ++rr) {
      const int row = row0 + rr, i = row & 2047;
      float cc[3];
      cc[0] = ldm(coords, (size_t)row * 3 + 0, mode) - CENTER;
      cc[1] = ldm(coords, (size_t)row * 3 + 1, mode) - CENTER;
      cc[2] = ldm(coords, (size_t)row * 3 + 2, mode) - CENTER;
      const float* sp = spro[rr];
      float a0, a1;
      if (isq) { a0 = qslot(h, 2 * w, sp, cc, wl, wc);
                 a1 = qslot(h, 2 * w + 1, sp, cc, wl, wc); }
      else     { a0 = kslot(h, 2 * w, sp, cc);
                 a1 = kslot(h, 2 * w + 1, sp, cc); }
      tab[((size_t)(b * 4 + h) * NN + i) * 48 + w] = pk2(a0, a1);
    }
  } else if (t < 496) {
    const int tt = t - 384;
    const int h = tt / 28, d = tt - h * 28;
    unsigned short* VTu = (unsigned short*)(ws + VT_OFF);
    #pragma unroll 1
    for (int rr = 0; rr < 4; ++rr) {
      const int row = row0 + rr, i = row & 2047;
      const float val = (d < 16) ? spro[rr][128 + h * 16 + d]
                                 : spro[rr][288 + h * 12 + (d - 16)];
      VTu[((size_t)((b * 4 + h) * 28 + d)) * NN + i] = f2bu(val);
    }
  } else if (t < 500) {
    const int h = t - 496;
    const float wc = softplus_f(ldm(w_c, h, mode));
    #pragma unroll 1
    for (int rr = 0; rr < 4; ++rr) {
      const int row = row0 + rr, i = row & 2047;
      float s = 0.f;
      #pragma unroll
      for (int e = 0; e < 12; ++e) {
        const float y = spro[rr][240 + h * 12 + e];
        s = fmaf(y, y, s);
      }
      ws[SB_OFF + (size_t)(b * 4 + h) * NN + i] = -0.5f * wc * s;
    }
  } else if (t == 500) {
    #pragma unroll 1
    for (int rr = 0; rr < 4; ++rr) {
      const int row = row0 + rr;
      float cc[3];
      cc[0] = ldm(coords, (size_t)row * 3 + 0, mode) - CENTER;
      cc[1] = ldm(coords, (size_t)row * 3 + 1, mode) - CENTER;
      cc[2] = ldm(coords, (size_t)row * 3 + 2, mode) - CENTER;
      ws[CQ_OFF + row] = fmaf(cc[0], cc[0], fmaf(cc[1], cc[1], cc[2] * cc[2]));
    }
  }
}

// ---------------------------------------------------------------------------
// Kernel B: MFMA flash attention. Deltas from passing round 14:
//   * jc 4 -> 8 (1024 blocks = 4 blocks/CU -> up to 32 waves/CU)
//   * double-buffered LDS, ONE barrier per j-tile (was 2): buf[(jt+1)&1] is
//     written only after the iter-jt barrier, by which point all reads of it
//     (iter jt-1) have completed — race-free by barrier ordering.
//   * prefetch depth 2: issue(jt+2) overlaps a full compute phase.
// grid (jc=8, it=16, bh=8), 512 threads.
// ---------------------------------------------------------------------------
__global__ __launch_bounds__(512) void attn_kernel(
    const uint32* __restrict__ QTg, const uint32* __restrict__ KTg,
    const uint32* __restrict__ VTg, const float* __restrict__ CQ,
    const float* __restrict__ SBt, float* __restrict__ parb)
{
  const int tid = threadIdx.x;
  const int lane = tid & 63;
  const int li = lane & 15, g = lane >> 4;
  const int jc = blockIdx.x;        // 0..7   (256 j)
  const int it = blockIdx.y;        // 0..15  (128 i)
  const int bh = blockIdx.z;        // 0..7
  const int b = bh >> 2;
  const int iloc = it * 128 + (tid >> 6) * 16 + li;
  const int j0base = jc * 256;

  const uint32* qrow = QTg + ((size_t)bh * NN + iloc) * 48;
  const bf16x8 B1 = *(const bf16x8*)(qrow + 4 * g);
  const bf16x8 B2 = *(const bf16x8*)(qrow + 16 + 4 * g);
  const bf16x8 B3 = *(const bf16x8*)(qrow + 32 + 4 * g);
  const float ciq = CQ[(size_t)b * NN + iloc];

  float m = -1e9f, l = 0.f;
  f32x4 acc0 = {0.f, 0.f, 0.f, 0.f};
  f32x4 acc1 = {0.f, 0.f, 0.f, 0.f};

  __shared__ uint32 sKT[2][32 * 52];   // [buf][32 j][104 bf16] padded rows
  __shared__ uint32 sVT[2][32 * 20];   // [buf][32 d][40 bf16], sigma-permuted
  __shared__ float  sCS[2][64];        // [buf][32 j][cjq, sbias]

  if (tid < 80) { sVT[0][560 + tid] = 0; sVT[1][560 + tid] = 0; }

  const float4* KT4 = (const float4*)(KTg + ((size_t)bh * NN + j0base) * 48);
  const float4* VT4 = (const float4*)VTg;
  const size_t vbase = (size_t)(bh * 28) * 256 + (j0base >> 3);

  float4 kreg = {0.f, 0.f, 0.f, 0.f};
  float4 vreg = {0.f, 0.f, 0.f, 0.f};
  float  creg = 0.f;
  const int kj = tid / 12, kq = tid - kj * 12;     // tid<384 role
  const int vd = tid >> 2, vq = tid & 3;           // tid<112 role
  const int cx = tid - 448, cj = cx & 31;          // tid>=448 role
  const int vA = (vq < 2) ? (8 * vq) : (8 * vq - 14);  // sigma chunk offsets

  auto issue = [&](int jt) {
    if (tid < 384) kreg = KT4[(size_t)jt * 384 + kj * 12 + kq];
    if (tid < 112) vreg = VT4[vbase + (size_t)vd * 256 + jt * 4 + vq];
    if (tid >= 448) {
      const int jg = j0base + jt * 32 + cj;
      creg = (cx < 32) ? CQ[(size_t)b * NN + jg] : SBt[(size_t)bh * NN + jg];
    }
  };
  auto wr = [&](int bsel) {
    if (tid < 384) *(float4*)(sKT[bsel] + kj * 52 + kq * 4) = kreg;
    if (tid < 112) {
      *(float2*)(sVT[bsel] + vd * 20 + vA)     = make_float2(vreg.x, vreg.y);
      *(float2*)(sVT[bsel] + vd * 20 + vA + 4) = make_float2(vreg.z, vreg.w);
    }
    if (tid >= 448) sCS[bsel][(cj << 1) | (cx >> 5)] = creg;
  };

  issue(0);
  wr(0);
  issue(1);

  #pragma unroll 1
  for (int jt = 0; jt < 8; ++jt) {
    const int cur = jt & 1;
    __syncthreads();                 // buf[cur] ready; reads of buf[cur^1] done
    if (jt + 1 < 8) wr(cur ^ 1);     // stage tile jt+1
    if (jt + 2 < 8) issue(jt + 2);   // prefetch tile jt+2 (spans full compute)

    float s[8];
    const f32x4 z = {0.f, 0.f, 0.f, 0.f};
    __builtin_amdgcn_s_setprio(1);
    #pragma unroll
    for (int h2 = 0; h2 < 2; ++h2) {
      const uint32* arow = sKT[cur] + (h2 * 16 + li) * 52;
      const bf16x8 A1 = *(const bf16x8*)(arow + 4 * g);
      const bf16x8 A2 = *(const bf16x8*)(arow + 16 + 4 * g);
      const bf16x8 A3 = *(const bf16x8*)(arow + 32 + 4 * g);
      f32x4 Cs = __builtin_amdgcn_mfma_f32_16x16x32_bf16(A1, B1, z, 0, 0, 0);
      Cs = __builtin_amdgcn_mfma_f32_16x16x32_bf16(A2, B2, Cs, 0, 0, 0);
      const f32x4 Cd = __builtin_amdgcn_mfma_f32_16x16x32_bf16(A3, B3, z, 0, 0, 0);
      #pragma unroll
      for (int r = 0; r < 4; ++r) {
        const int jj = h2 * 16 + g * 4 + r;
        const float cjq = sCS[cur][jj * 2], sb = sCS[cur][jj * 2 + 1];
        const float d2 = fmaf(-2.f, Cd[r], ciq + cjq);
        const float sv = Cs[r] + sb;
        s[h2 * 4 + r] = (d2 > 100.f) ? -1e30f : sv;
      }
    }
    __builtin_amdgcn_s_setprio(0);

    float smax = fmaxf(fmaxf(fmaxf(s[0], s[1]), fmaxf(s[2], s[3])),
                       fmaxf(fmaxf(s[4], s[5]), fmaxf(s[6], s[7])));
    smax = fmaxf(smax, __shfl_xor(smax, 16));
    smax = fmaxf(smax, __shfl_xor(smax, 32));
    const float mnew = fmaxf(m, smax);
    const float alpha = __expf(m - mnew);
    m = mnew;
    l *= alpha; acc0 *= alpha; acc1 *= alpha;
    float p[8];
    #pragma unroll
    for (int k = 0; k < 8; ++k) p[k] = __expf(s[k] - m);
    l += ((p[0] + p[1]) + (p[2] + p[3])) + ((p[4] + p[5]) + (p[6] + p[7]));

    // PV B-operand built entirely in-register (sigma-matched V staging)
    union { uint32 u[4]; bf16x8 v; } bp;
    bp.u[0] = pk2(p[0], p[1]); bp.u[1] = pk2(p[2], p[3]);
    bp.u[2] = pk2(p[4], p[5]); bp.u[3] = pk2(p[6], p[7]);

    const bf16x8 Av0 = *(const bf16x8*)(sVT[cur] + li * 20 + 4 * g);
    const bf16x8 Av1 = *(const bf16x8*)(sVT[cur] + (16 + li) * 20 + 4 * g);
    __builtin_amdgcn_s_setprio(1);
    acc0 = __builtin_amdgcn_mfma_f32_16x16x32_bf16(Av0, bp.v, acc0, 0, 0, 0);
    acc1 = __builtin_amdgcn_mfma_f32_16x16x32_bf16(Av1, bp.v, acc1, 0, 0, 0);
    __builtin_amdgcn_s_setprio(0);
  }

  l += __shfl_xor(l, 16);
  l += __shfl_xor(l, 32);

  float* rec = parb + ((size_t)(bh * 8 + jc) * NN + iloc) * 16;
  rec[0] = m; rec[1] = l;                    // 4 lanes write same values
  uint32* ru = (uint32*)(rec + 2);
  ru[2 * g]     = pk2(acc0[0], acc0[1]);     // slot s holds acc[2s],acc[2s+1]
  ru[2 * g + 1] = pk2(acc0[2], acc0[3]);
  if (g < 3) {
    ru[8 + 2 * g]     = pk2(acc1[0], acc1[1]);
    ru[8 + 2 * g + 1] = pk2(acc1[2], acc1[3]);
  }
}

// ---------------------------------------------------------------------------
// Kernel C: fused combine + output GEMM (proven round 14; 8 partial chunks).
// ---------------------------------------------------------------------------
__global__ __launch_bounds__(256) void out_kernel(
    const float* __restrict__ parb, const void* Wo, const void* bo,
    const unsigned short* __restrict__ ufeat, void* outp)
{
  const int t = threadIdx.x;
  const int blk = blockIdx.x;
  __shared__ int scnt;
  __shared__ float si[4 * 112];
  __shared__ float sM[16], sIL[16];

  if (t == 0) scnt = 0;
  __syncthreads();
  {
    const unsigned e = (ufeat[t] >> 7) & 0xFFu;
    const unsigned long long bl = __ballot(e >= 0xC0u);
    if ((t & 63) == 0) atomicAdd(&scnt, (int)__popcll(bl));
  }
  __syncthreads();
  const int mode = (scnt > 8) ? 1 : 0;

  if (t < 16) {
    const int lr = t >> 2, h = t & 3;
    const int row = blk * 4 + lr, b = row >> 11, i = row & 2047;
    const int bh = b * 4 + h;
    const float* base = parb + ((size_t)(bh * 8) * NN + i) * 16;
    float M = -1e9f;
    #pragma unroll
    for (int c = 0; c < 8; ++c) M = fmaxf(M, base[(size_t)c * NN * 16]);
    float L = 0.f;
    #pragma unroll
    for (int c = 0; c < 8; ++c) {
      const float* r = base + (size_t)c * NN * 16;
      L = fmaf(r[1], __expf(r[0] - M), L);
    }
    sM[t] = M; sIL[t] = 1.f / L;
  }
  __syncthreads();

  if (t < 224) {
    const int u = t / 14, pr = t - u * 14;   // u: (lr,h) 0..15, pr: pair 0..13
    const int lr = u >> 2, h = u & 3;
    const int row = blk * 4 + lr, b = row >> 11, i = row & 2047;
    const int bh = b * 4 + h;
    const float* base = parb + ((size_t)(bh * 8) * NN + i) * 16;
    const float M = sM[u], iL = sIL[u];
    float o0 = 0.f, o1 = 0.f;
    #pragma unroll
    for (int c = 0; c < 8; ++c) {
      const float* r = base + (size_t)c * NN * 16;
      const float wgt = __expf(r[0] - M);
      const float2 f = upk2(((const unsigned*)(r + 2))[pr]);
      o0 = fmaf(f.x, wgt, o0); o1 = fmaf(f.y, wgt, o1);
    }
    const int d = 2 * pr;
    const int col = (d < 16) ? (h * 16 + d) : (64 + h * 12 + (d - 16));
    si[lr * 112 + col]     = o0 * iL;
    si[lr * 112 + col + 1] = o1 * iL;
  }
  __syncthreads();

  const int lr = t >> 6, c = t & 63;
  float acc = mode ? ((const float*)bo)[c] : b2f(((const bf16*)bo)[c]);
  if (mode) {
    const float* Wf = (const float*)Wo;
    #pragma unroll 16
    for (int kk = 0; kk < 112; ++kk)
      acc = fmaf(si[lr * 112 + kk], Wf[(size_t)kk * 64 + c], acc);
  } else {
    const bf16* Wb = (const bf16*)Wo;
    #pragma unroll 16
    for (int kk = 0; kk < 112; ++kk)
      acc = fmaf(si[lr * 112 + kk], b2f(Wb[(size_t)kk * 64 + c]), acc);
  }
  const size_t oi = (size_t)(blk * 4 + lr) * 64 + c;
  if (mode) ((float*)outp)[oi] = acc;
  else      ((bf16*)outp)[oi] = __float2bfloat16(acc);
}

extern "C" void kernel_launch(void* const* d_in, const int* in_sizes, int n_in,
                              void* d_out, int out_size, void* d_ws, size_t ws_size,
                              hipStream_t stream)
{
  float* ws = (float*)d_ws;

  proj_kernel<<<BB * NN / 4, 512, 0, stream>>>(d_in[0], d_in[1], d_in[2], d_in[3],
      d_in[4], d_in[5], d_in[6], d_in[7], d_in[8], d_in[9], d_in[10], d_in[11],
      d_in[12], d_in[13], d_in[16], d_in[17], ws);

  attn_kernel<<<dim3(8, 16, 8), 512, 0, stream>>>(
      (const uint32*)(ws + QT_OFF), (const uint32*)(ws + KT_OFF),
      (const uint32*)(ws + VT_OFF), ws + CQ_OFF, ws + SB_OFF, ws + PAR_OFF);

  out_kernel<<<(BB * NN) / 4, 256, 0, stream>>>(
      ws + PAR_OFF, d_in[14], d_in[15], (const unsigned short*)d_in[0], d_out);
}

// Round 16
// 55.771 us; speedup vs baseline: 1.0812x; 1.0812x over previous
//
#include <hip/hip_runtime.h>
#include <hip/hip_bf16.h>

typedef __hip_bfloat16 bf16;
typedef unsigned int uint32;
typedef __attribute__((ext_vector_type(8))) short bf16x8;
typedef __attribute__((ext_vector_type(4))) float f32x4;

#define BB 2
#define NN 2048
#define CENTER 15.0f

// workspace float offsets (end = 3,330,064 f32 = 13.3 MB)
#define QT_OFF   16u       // u32 view [8 bh][2048 i][48]  (96 bf16 slots)
#define KT_OFF   786448u   // u32 view [8 bh][2048 j][48]
#define VT_OFF   1572880u  // u16 view [8 bh][28 d][2048 j]
#define CQ_OFF   1802256u  // f32 [4096]         |c-15|^2
#define SB_OFF   1806352u  // f32 [8 bh][2048]   -0.5*wc*|kp_c|^2
#define PAR_OFF  2281488u  // f32 [8 bh][4 jc][2048][16]

__device__ __forceinline__ float b2f(bf16 x) { return __bfloat162float(x); }

__device__ __forceinline__ float ldm(const void* p, size_t i, int mode) {
  return mode ? ((const float*)p)[i] : b2f(((const bf16*)p)[i]);
}

__device__ __forceinline__ float softplus_f(float x) {
  return (x > 20.f) ? x : log1pf(__expf(x));
}

__device__ __forceinline__ unsigned pk2(float a, float b) {
  union { __hip_bfloat162 v; unsigned u; } cv;
  cv.v.x = __float2bfloat16(a); cv.v.y = __float2bfloat16(b);
  return cv.u;
}
__device__ __forceinline__ float2 upk2(unsigned u) {
  union { unsigned u; __hip_bfloat162 v; } cv; cv.u = u;
  return make_float2(__bfloat162float(cv.v.x), __bfloat162float(cv.v.y));
}
__device__ __forceinline__ unsigned short f2bu(float x) {
  union { bf16 b; unsigned short u; } c; c.b = __float2bfloat16(x); return c.u;
}
__device__ __forceinline__ float lo_part(float x) {
  return x - __bfloat162float(__float2bfloat16(x));
}

// MFMA table slot builders (proven rounds 11-14).
__device__ float qslot(int h, int s, const float* spro, const float* cc,
                       float wl, float wc) {
  if (s < 16) return wl * spro[h * 16 + s];
  if (s < 28) return wc * spro[192 + h * 12 + (s - 16)];
  if (s < 32) return 0.f;
  if (s < 44) return wc * spro[192 + h * 12 + (s - 32)];
  if (s < 56) return lo_part(wc * spro[192 + h * 12 + (s - 44)]);
  if (s < 64) return 0.f;
  if (s < 67) return cc[s - 64];
  if (s < 70) return cc[s - 67];
  if (s < 73) return lo_part(cc[s - 70]);
  return 0.f;
}
__device__ float kslot(int h, int s, const float* spro, const float* cc) {
  if (s < 16) return spro[64 + h * 16 + s];
  if (s < 28) return spro[240 + h * 12 + (s - 16)];
  if (s < 32) return 0.f;
  if (s < 44) return lo_part(spro[240 + h * 12 + (s - 32)]);
  if (s < 56) return spro[240 + h * 12 + (s - 44)];
  if (s < 64) return 0.f;
  if (s < 67) return cc[s - 64];
  if (s < 70) return lo_part(cc[s - 67]);
  if (s < 73) return cc[s - 70];
  return 0.f;
}

// ---------------------------------------------------------------------------
// Kernel A: projections + MFMA table packing (verbatim from passing round 14).
// 4 rows/block (grid 1024 x 512); in-block dtype detect.
// ---------------------------------------------------------------------------
__global__ __launch_bounds__(512) void proj_kernel(
    const void* feat, const void* coords,
    const void* Wq,  const void* bq,  const void* Wk,  const void* bk,
    const void* Wv,  const void* bv,  const void* Wqp, const void* bqp,
    const void* Wkp, const void* bkp, const void* Wvp, const void* bvp,
    const void* w_c, const void* w_l, float* ws)
{
  const int t = threadIdx.x;
  const int row0 = blockIdx.x * 4;
  const int b = row0 >> 11;
  __shared__ int scnt;
  __shared__ float sfT[64 * 4];       // [f][rr]
  __shared__ float spro[4][336];

  if (t == 0) scnt = 0;
  __syncthreads();
  {
    const unsigned short uv = ((const unsigned short*)feat)[t];
    const unsigned e = (uv >> 7) & 0xFFu;
    const unsigned long long bl = __ballot(e >= 0xC0u);
    if ((t & 63) == 0) atomicAdd(&scnt, (int)__popcll(bl));
  }
  __syncthreads();
  const int mode = (scnt > 16) ? 1 : 0;

  if (t < 256) {
    const int rr = t >> 6, f = t & 63;
    sfT[f * 4 + rr] = ldm(feat, (size_t)(row0 + rr) * 64 + f, mode);
  }
  __syncthreads();

  if (t < 336) {
    const void *W, *bias; int odim, c, cls, ofs;
    if (t < 64)       { W = Wq;  bias = bq;  odim = 64; c = t;       cls = 0; ofs = 0; }
    else if (t < 128) { W = Wk;  bias = bk;  odim = 64; c = t - 64;  cls = 1; ofs = 64; }
    else if (t < 192) { W = Wv;  bias = bv;  odim = 64; c = t - 128; cls = 2; ofs = 128; }
    else if (t < 240) { W = Wqp; bias = bqp; odim = 48; c = t - 192; cls = 3; ofs = 192; }
    else if (t < 288) { W = Wkp; bias = bkp; odim = 48; c = t - 240; cls = 4; ofs = 240; }
    else              { W = Wvp; bias = bvp; odim = 48; c = t - 288; cls = 5; ofs = 288; }
    const float bb = ldm(bias, c, mode);
    float a0 = bb, a1 = bb, a2 = bb, a3 = bb;
    if (mode) {
      const float* Wf = (const float*)W;
      #pragma unroll 8
      for (int f = 0; f < 64; ++f) {
        const float wf = Wf[(size_t)f * odim + c];
        const float4 fv = *(const float4*)(sfT + f * 4);
        a0 = fmaf(fv.x, wf, a0); a1 = fmaf(fv.y, wf, a1);
        a2 = fmaf(fv.z, wf, a2); a3 = fmaf(fv.w, wf, a3);
      }
    } else {
      const bf16* Wb = (const bf16*)W;
      #pragma unroll 8
      for (int f = 0; f < 64; ++f) {
        const float wf = b2f(Wb[(size_t)f * odim + c]);
        const float4 fv = *(const float4*)(sfT + f * 4);
        a0 = fmaf(fv.x, wf, a0); a1 = fmaf(fv.y, wf, a1);
        a2 = fmaf(fv.z, wf, a2); a3 = fmaf(fv.w, wf, a3);
      }
    }
    float av[4] = {a0, a1, a2, a3};
    #pragma unroll
    for (int rr = 0; rr < 4; ++rr) {
      float acc = av[rr];
      if (cls >= 3) {
        acc += ldm(coords, (size_t)(row0 + rr) * 3 + (c % 3), mode);
        if (cls == 3 || cls == 4) acc -= CENTER;   // center qp,kp (shift-inv)
      }
      spro[rr][ofs + c] = acc;
    }
  }
  __syncthreads();

  if (t < 384) {
    const bool isq = (t < 192);
    const int per = isq ? t : t - 192;
    const int h = per / 48, w = per - h * 48;
    const float wl = softplus_f(ldm(w_l, h, mode)) * 0.25f;
    const float wc = softplus_f(ldm(w_c, h, mode));
    uint32* tab = (uint32*)(ws + (isq ? QT_OFF : KT_OFF));
    #pragma unroll 1
    for (int rr = 0; rr < 4; ++rr) {
      const int row = row0 + rr, i = row & 2047;
      float cc[3];
      cc[0] = ldm(coords, (size_t)row * 3 + 0, mode) - CENTER;
      cc[1] = ldm(coords, (size_t)row * 3 + 1, mode) - CENTER;
      cc[2] = ldm(coords, (size_t)row * 3 + 2, mode) - CENTER;
      const float* sp = spro[rr];
      float a0, a1;
      if (isq) { a0 = qslot(h, 2 * w, sp, cc, wl, wc);
                 a1 = qslot(h, 2 * w + 1, sp, cc, wl, wc); }
      else     { a0 = kslot(h, 2 * w, sp, cc);
                 a1 = kslot(h, 2 * w + 1, sp, cc); }
      tab[((size_t)(b * 4 + h) * NN + i) * 48 + w] = pk2(a0, a1);
    }
  } else if (t < 496) {
    const int tt = t - 384;
    const int h = tt / 28, d = tt - h * 28;
    unsigned short* VTu = (unsigned short*)(ws + VT_OFF);
    #pragma unroll 1
    for (int rr = 0; rr < 4; ++rr) {
      const int row = row0 + rr, i = row & 2047;
      const float val = (d < 16) ? spro[rr][128 + h * 16 + d]
                                 : spro[rr][288 + h * 12 + (d - 16)];
      VTu[((size_t)((b * 4 + h) * 28 + d)) * NN + i] = f2bu(val);
    }
  } else if (t < 500) {
    const int h = t - 496;
    const float wc = softplus_f(ldm(w_c, h, mode));
    #pragma unroll 1
    for (int rr = 0; rr < 4; ++rr) {
      const int row = row0 + rr, i = row & 2047;
      float s = 0.f;
      #pragma unroll
      for (int e = 0; e < 12; ++e) {
        const float y = spro[rr][240 + h * 12 + e];
        s = fmaf(y, y, s);
      }
      ws[SB_OFF + (size_t)(b * 4 + h) * NN + i] = -0.5f * wc * s;
    }
  } else if (t == 500) {
    #pragma unroll 1
    for (int rr = 0; rr < 4; ++rr) {
      const int row = row0 + rr;
      float cc[3];
      cc[0] = ldm(coords, (size_t)row * 3 + 0, mode) - CENTER;
      cc[1] = ldm(coords, (size_t)row * 3 + 1, mode) - CENTER;
      cc[2] = ldm(coords, (size_t)row * 3 + 2, mode) - CENTER;
      ws[CQ_OFF + row] = fmaf(cc[0], cc[0], fmaf(cc[1], cc[1], cc[2] * cc[2]));
    }
  }
}

// ---------------------------------------------------------------------------
// Kernel B: MFMA flash attention — round-14 config (jc=4, 512 blocks, 16
// j-tiles/block) with ONE isolated delta: double-buffered LDS, single
// barrier per j-tile (was 2), prefetch depth 2. Race-free: buf[cur^1] is
// written only after the iter-jt barrier, by which point all reads of it
// (iter jt-1) have completed.
// grid (jc=4, it=16, bh=8), 512 threads.
// ---------------------------------------------------------------------------
__global__ __launch_bounds__(512) void attn_kernel(
    const uint32* __restrict__ QTg, const uint32* __restrict__ KTg,
    const uint32* __restrict__ VTg, const float* __restrict__ CQ,
    const float* __restrict__ SBt, float* __restrict__ parb)
{
  const int tid = threadIdx.x;
  const int lane = tid & 63;
  const int li = lane & 15, g = lane >> 4;
  const int jc = blockIdx.x;        // 0..3   (512 j)
  const int it = blockIdx.y;        // 0..15  (128 i)
  const int bh = blockIdx.z;        // 0..7
  const int b = bh >> 2;
  const int iloc = it * 128 + (tid >> 6) * 16 + li;
  const int j0base = jc * 512;

  const uint32* qrow = QTg + ((size_t)bh * NN + iloc) * 48;
  const bf16x8 B1 = *(const bf16x8*)(qrow + 4 * g);
  const bf16x8 B2 = *(const bf16x8*)(qrow + 16 + 4 * g);
  const bf16x8 B3 = *(const bf16x8*)(qrow + 32 + 4 * g);
  const float ciq = CQ[(size_t)b * NN + iloc];

  float m = -1e9f, l = 0.f;
  f32x4 acc0 = {0.f, 0.f, 0.f, 0.f};
  f32x4 acc1 = {0.f, 0.f, 0.f, 0.f};

  __shared__ uint32 sKT[2][32 * 52];   // [buf][32 j][104 bf16] padded rows
  __shared__ uint32 sVT[2][32 * 20];   // [buf][32 d][40 bf16], sigma-permuted
  __shared__ float  sCS[2][64];        // [buf][32 j][cjq, sbias]

  if (tid < 80) { sVT[0][560 + tid] = 0; sVT[1][560 + tid] = 0; }

  const float4* KT4 = (const float4*)(KTg + ((size_t)bh * NN + j0base) * 48);
  const float4* VT4 = (const float4*)VTg;
  const size_t vbase = (size_t)(bh * 28) * 256 + (j0base >> 3);

  float4 kreg = {0.f, 0.f, 0.f, 0.f};
  float4 vreg = {0.f, 0.f, 0.f, 0.f};
  float  creg = 0.f;
  const int kj = tid / 12, kq = tid - kj * 12;     // tid<384 role
  const int vd = tid >> 2, vq = tid & 3;           // tid<112 role
  const int cx = tid - 448, cj = cx & 31;          // tid>=448 role
  const int vA = (vq < 2) ? (8 * vq) : (8 * vq - 14);  // sigma chunk offsets

  auto issue = [&](int jt) {
    if (tid < 384) kreg = KT4[(size_t)jt * 384 + kj * 12 + kq];
    if (tid < 112) vreg = VT4[vbase + (size_t)vd * 256 + jt * 4 + vq];
    if (tid >= 448) {
      const int jg = j0base + jt * 32 + cj;
      creg = (cx < 32) ? CQ[(size_t)b * NN + jg] : SBt[(size_t)bh * NN + jg];
    }
  };
  auto wr = [&](int bsel) {
    if (tid < 384) *(float4*)(sKT[bsel] + kj * 52 + kq * 4) = kreg;
    if (tid < 112) {
      *(float2*)(sVT[bsel] + vd * 20 + vA)     = make_float2(vreg.x, vreg.y);
      *(float2*)(sVT[bsel] + vd * 20 + vA + 4) = make_float2(vreg.z, vreg.w);
    }
    if (tid >= 448) sCS[bsel][(cj << 1) | (cx >> 5)] = creg;
  };

  issue(0);
  wr(0);
  issue(1);

  #pragma unroll 1
  for (int jt = 0; jt < 16; ++jt) {
    const int cur = jt & 1;
    __syncthreads();                  // buf[cur] ready; reads of buf[cur^1] done
    if (jt + 1 < 16) wr(cur ^ 1);     // stage tile jt+1
    if (jt + 2 < 16) issue(jt + 2);   // prefetch tile jt+2 (spans full compute)

    float s[8];
    const f32x4 z = {0.f, 0.f, 0.f, 0.f};
    __builtin_amdgcn_s_setprio(1);
    #pragma unroll
    for (int h2 = 0; h2 < 2; ++h2) {
      const uint32* arow = sKT[cur] + (h2 * 16 + li) * 52;
      const bf16x8 A1 = *(const bf16x8*)(arow + 4 * g);
      const bf16x8 A2 = *(const bf16x8*)(arow + 16 + 4 * g);
      const bf16x8 A3 = *(const bf16x8*)(arow + 32 + 4 * g);
      f32x4 Cs = __builtin_amdgcn_mfma_f32_16x16x32_bf16(A1, B1, z, 0, 0, 0);
      Cs = __builtin_amdgcn_mfma_f32_16x16x32_bf16(A2, B2, Cs, 0, 0, 0);
      const f32x4 Cd = __builtin_amdgcn_mfma_f32_16x16x32_bf16(A3, B3, z, 0, 0, 0);
      #pragma unroll
      for (int r = 0; r < 4; ++r) {
        const int jj = h2 * 16 + g * 4 + r;
        const float cjq = sCS[cur][jj * 2], sb = sCS[cur][jj * 2 + 1];
        const float d2 = fmaf(-2.f, Cd[r], ciq + cjq);
        const float sv = Cs[r] + sb;
        s[h2 * 4 + r] = (d2 > 100.f) ? -1e30f : sv;
      }
    }
    __builtin_amdgcn_s_setprio(0);

    float smax = fmaxf(fmaxf(fmaxf(s[0], s[1]), fmaxf(s[2], s[3])),
                       fmaxf(fmaxf(s[4], s[5]), fmaxf(s[6], s[7])));
    smax = fmaxf(smax, __shfl_xor(smax, 16));
    smax = fmaxf(smax, __shfl_xor(smax, 32));
    const float mnew = fmaxf(m, smax);
    const float alpha = __expf(m - mnew);
    m = mnew;
    l *= alpha; acc0 *= alpha; acc1 *= alpha;
    float p[8];
    #pragma unroll
    for (int k = 0; k < 8; ++k) p[k] = __expf(s[k] - m);
    l += ((p[0] + p[1]) + (p[2] + p[3])) + ((p[4] + p[5]) + (p[6] + p[7]));

    // PV B-operand built entirely in-register (sigma-matched V staging)
    union { uint32 u[4]; bf16x8 v; } bp;
    bp.u[0] = pk2(p[0], p[1]); bp.u[1] = pk2(p[2], p[3]);
    bp.u[2] = pk2(p[4], p[5]); bp.u[3] = pk2(p[6], p[7]);

    const bf16x8 Av0 = *(const bf16x8*)(sVT[cur] + li * 20 + 4 * g);
    const bf16x8 Av1 = *(const bf16x8*)(sVT[cur] + (16 + li) * 20 + 4 * g);
    __builtin_amdgcn_s_setprio(1);
    acc0 = __builtin_amdgcn_mfma_f32_16x16x32_bf16(Av0, bp.v, acc0, 0, 0, 0);
    acc1 = __builtin_amdgcn_mfma_f32_16x16x32_bf16(Av1, bp.v, acc1, 0, 0, 0);
    __builtin_amdgcn_s_setprio(0);
  }

  l += __shfl_xor(l, 16);
  l += __shfl_xor(l, 32);

  float* rec = parb + ((size_t)(bh * 4 + jc) * NN + iloc) * 16;
  rec[0] = m; rec[1] = l;                    // 4 lanes write same values
  uint32* ru = (uint32*)(rec + 2);
  ru[2 * g]     = pk2(acc0[0], acc0[1]);     // slot s holds acc[2s],acc[2s+1]
  ru[2 * g + 1] = pk2(acc0[2], acc0[3]);
  if (g < 3) {
    ru[8 + 2 * g]     = pk2(acc1[0], acc1[1]);
    ru[8 + 2 * g + 1] = pk2(acc1[2], acc1[3]);
  }
}

// ---------------------------------------------------------------------------
// Kernel C: fused combine + output GEMM (verbatim from passing round 14;
// 4 partial chunks).
// ---------------------------------------------------------------------------
__global__ __launch_bounds__(256) void out_kernel(
    const float* __restrict__ parb, const void* Wo, const void* bo,
    const unsigned short* __restrict__ ufeat, void* outp)
{
  const int t = threadIdx.x;
  const int blk = blockIdx.x;
  __shared__ int scnt;
  __shared__ float si[4 * 112];
  __shared__ float sM[16], sIL[16];

  if (t == 0) scnt = 0;
  __syncthreads();
  {
    const unsigned e = (ufeat[t] >> 7) & 0xFFu;
    const unsigned long long bl = __ballot(e >= 0xC0u);
    if ((t & 63) == 0) atomicAdd(&scnt, (int)__popcll(bl));
  }
  __syncthreads();
  const int mode = (scnt > 8) ? 1 : 0;

  if (t < 16) {
    const int lr = t >> 2, h = t & 3;
    const int row = blk * 4 + lr, b = row >> 11, i = row & 2047;
    const int bh = b * 4 + h;
    const float* base = parb + ((size_t)(bh * 4) * NN + i) * 16;
    float M = -1e9f;
    #pragma unroll
    for (int c = 0; c < 4; ++c) M = fmaxf(M, base[(size_t)c * NN * 16]);
    float L = 0.f;
    #pragma unroll
    for (int c = 0; c < 4; ++c) {
      const float* r = base + (size_t)c * NN * 16;
      L = fmaf(r[1], __expf(r[0] - M), L);
    }
    sM[t] = M; sIL[t] = 1.f / L;
  }
  __syncthreads();

  if (t < 224) {
    const int u = t / 14, pr = t - u * 14;   // u: (lr,h) 0..15, pr: pair 0..13
    const int lr = u >> 2, h = u & 3;
    const int row = blk * 4 + lr, b = row >> 11, i = row & 2047;
    const int bh = b * 4 + h;
    const float* base = parb + ((size_t)(bh * 4) * NN + i) * 16;
    const float M = sM[u], iL = sIL[u];
    float o0 = 0.f, o1 = 0.f;
    #pragma unroll
    for (int c = 0; c < 4; ++c) {
      const float* r = base + (size_t)c * NN * 16;
      const float wgt = __expf(r[0] - M);
      const float2 f = upk2(((const unsigned*)(r + 2))[pr]);
      o0 = fmaf(f.x, wgt, o0); o1 = fmaf(f.y, wgt, o1);
    }
    const int d = 2 * pr;
    const int col = (d < 16) ? (h * 16 + d) : (64 + h * 12 + (d - 16));
    si[lr * 112 + col]     = o0 * iL;
    si[lr * 112 + col + 1] = o1 * iL;
  }
  __syncthreads();

  const int lr = t >> 6, c = t & 63;
  float acc = mode ? ((const float*)bo)[c] : b2f(((const bf16*)bo)[c]);
  if (mode) {
    const float* Wf = (const float*)Wo;
    #pragma unroll 16
    for (int kk = 0; kk < 112; ++kk)
      acc = fmaf(si[lr * 112 + kk], Wf[(size_t)kk * 64 + c], acc);
  } else {
    const bf16* Wb = (const bf16*)Wo;
    #pragma unroll 16
    for (int kk = 0; kk < 112; ++kk)
      acc = fmaf(si[lr * 112 + kk], b2f(Wb[(size_t)kk * 64 + c]), acc);
  }
  const size_t oi = (size_t)(blk * 4 + lr) * 64 + c;
  if (mode) ((float*)outp)[oi] = acc;
  else      ((bf16*)outp)[oi] = __float2bfloat16(acc);
}

extern "C" void kernel_launch(void* const* d_in, const int* in_sizes, int n_in,
                              void* d_out, int out_size, void* d_ws, size_t ws_size,
                              hipStream_t stream)
{
  float* ws = (float*)d_ws;

  proj_kernel<<<BB * NN / 4, 512, 0, stream>>>(d_in[0], d_in[1], d_in[2], d_in[3],
      d_in[4], d_in[5], d_in[6], d_in[7], d_in[8], d_in[9], d_in[10], d_in[11],
      d_in[12], d_in[13], d_in[16], d_in[17], ws);

  attn_kernel<<<dim3(4, 16, 8), 512, 0, stream>>>(
      (const uint32*)(ws + QT_OFF), (const uint32*)(ws + KT_OFF),
      (const uint32*)(ws + VT_OFF), ws + CQ_OFF, ws + SB_OFF, ws + PAR_OFF);

  out_kernel<<<(BB * NN) / 4, 256, 0, stream>>>(
      ws + PAR_OFF, d_in[14], d_in[15], (const unsigned short*)d_in[0], d_out);
}

// Round 17
// 54.789 us; speedup vs baseline: 1.1006x; 1.0179x over previous
//
#include <hip/hip_runtime.h>
#include <hip/hip_bf16.h>

typedef __hip_bfloat16 bf16;
typedef unsigned int uint32;
typedef __attribute__((ext_vector_type(8))) short bf16x8;
typedef __attribute__((ext_vector_type(4))) float f32x4;

#define BB 2
#define NN 2048
#define CENTER 15.0f

// workspace float offsets (end = 3,330,064 f32 = 13.3 MB)
#define QT_OFF   16u       // u32 view [8 bh][2048 i][48]  (96 bf16 slots)
#define KT_OFF   786448u   // u32 view [8 bh][2048 j][48]
#define VT_OFF   1572880u  // u16 view [8 bh][28 d][2048 j]
#define PAR_OFF  2281488u  // f32 [8 bh][4 jc][2048][16]

__device__ __forceinline__ float b2f(bf16 x) { return __bfloat162float(x); }

__device__ __forceinline__ float ldm(const void* p, size_t i, int mode) {
  return mode ? ((const float*)p)[i] : b2f(((const bf16*)p)[i]);
}

__device__ __forceinline__ float softplus_f(float x) {
  return (x > 20.f) ? x : log1pf(__expf(x));
}

__device__ __forceinline__ unsigned pk2(float a, float b) {
  union { __hip_bfloat162 v; unsigned u; } cv;
  cv.v.x = __float2bfloat16(a); cv.v.y = __float2bfloat16(b);
  return cv.u;
}
__device__ __forceinline__ float2 upk2(unsigned u) {
  union { unsigned u; __hip_bfloat162 v; } cv; cv.u = u;
  return make_float2(__bfloat162float(cv.v.x), __bfloat162float(cv.v.y));
}
__device__ __forceinline__ unsigned short f2bu(float x) {
  union { bf16 b; unsigned short u; } c; c.b = __float2bfloat16(x); return c.u;
}
__device__ __forceinline__ float lo_part(float x) {
  return x - __bfloat162float(__float2bfloat16(x));
}

// MFMA table slot builders. NEW this round (folds into free slots):
//  Cs chain  (slots 0-63):  28/29 = sb_hi/lo (k-side) x 1.0 (q-side)
//                           -> Cs = full logit incl. -0.5*wc*|kp|^2 bias
//  Cd chain  (slots 64-95): 73/74 = 1.0 (k) x hi/lo(-0.5*ciq) (q)
//                           75/76 = hi/lo(cjq) (k) x -0.5 (q)
//                           -> Cd = Sum ci*cj - 0.5*(ciq+cjq) = -0.5*d^2
//  mask becomes: d2 > 100  <=>  Cd < -50.
__device__ float qslot(int h, int s, const float* spro, const float* cc,
                       float wl, float wc) {
  if (s < 16) return wl * spro[h * 16 + s];
  if (s < 28) return wc * spro[192 + h * 12 + (s - 16)];
  if (s < 30) return 1.f;                    // pairs sb_hi / sb_lo
  if (s < 32) return 0.f;
  if (s < 44) return wc * spro[192 + h * 12 + (s - 32)];
  if (s < 56) return lo_part(wc * spro[192 + h * 12 + (s - 44)]);
  if (s < 64) return 0.f;
  if (s < 67) return cc[s - 64];
  if (s < 70) return cc[s - 67];
  if (s < 73) return lo_part(cc[s - 70]);
  if (s < 75) {                              // -0.5*ciq hi/lo, pairs 1.0
    const float ciq = -0.5f * fmaf(cc[0], cc[0],
                        fmaf(cc[1], cc[1], cc[2] * cc[2]));
    return (s == 73) ? ciq : lo_part(ciq);
  }
  if (s < 77) return -0.5f;                  // pairs cjq_hi / cjq_lo
  return 0.f;
}
__device__ float kslot(int h, int s, const float* spro, const float* cc,
                       float wc) {
  if (s < 16) return spro[64 + h * 16 + s];
  if (s < 28) return spro[240 + h * 12 + (s - 16)];
  if (s < 30) {                              // sb = -0.5*wc*|kp_c|^2 hi/lo
    float sb = 0.f;
    #pragma unroll
    for (int e = 0; e < 12; ++e) {
      const float y = spro[240 + h * 12 + e];
      sb = fmaf(y, y, sb);
    }
    sb *= -0.5f * wc;
    return (s == 28) ? sb : lo_part(sb);
  }
  if (s < 32) return 0.f;
  if (s < 44) return lo_part(spro[240 + h * 12 + (s - 32)]);
  if (s < 56) return spro[240 + h * 12 + (s - 44)];
  if (s < 64) return 0.f;
  if (s < 67) return cc[s - 64];
  if (s < 70) return lo_part(cc[s - 67]);
  if (s < 73) return cc[s - 70];
  if (s < 75) return 1.f;                    // pairs -0.5*ciq hi/lo
  if (s < 77) {                              // cjq hi/lo, pairs -0.5
    const float cjq = fmaf(cc[0], cc[0], fmaf(cc[1], cc[1], cc[2] * cc[2]));
    return (s == 75) ? cjq : lo_part(cjq);
  }
  return 0.f;
}

// ---------------------------------------------------------------------------
// Kernel A: projections + MFMA table packing. 4 rows/block (grid 1024 x 512);
// in-block dtype detect. CQ/SB side tables no longer needed (folded).
// ---------------------------------------------------------------------------
__global__ __launch_bounds__(512) void proj_kernel(
    const void* feat, const void* coords,
    const void* Wq,  const void* bq,  const void* Wk,  const void* bk,
    const void* Wv,  const void* bv,  const void* Wqp, const void* bqp,
    const void* Wkp, const void* bkp, const void* Wvp, const void* bvp,
    const void* w_c, const void* w_l, float* ws)
{
  const int t = threadIdx.x;
  const int row0 = blockIdx.x * 4;
  const int b = row0 >> 11;
  __shared__ int scnt;
  __shared__ float sfT[64 * 4];       // [f][rr]
  __shared__ float spro[4][336];

  if (t == 0) scnt = 0;
  __syncthreads();
  {
    const unsigned short uv = ((const unsigned short*)feat)[t];
    const unsigned e = (uv >> 7) & 0xFFu;
    const unsigned long long bl = __ballot(e >= 0xC0u);
    if ((t & 63) == 0) atomicAdd(&scnt, (int)__popcll(bl));
  }
  __syncthreads();
  const int mode = (scnt > 16) ? 1 : 0;

  if (t < 256) {
    const int rr = t >> 6, f = t & 63;
    sfT[f * 4 + rr] = ldm(feat, (size_t)(row0 + rr) * 64 + f, mode);
  }
  __syncthreads();

  if (t < 336) {
    const void *W, *bias; int odim, c, cls, ofs;
    if (t < 64)       { W = Wq;  bias = bq;  odim = 64; c = t;       cls = 0; ofs = 0; }
    else if (t < 128) { W = Wk;  bias = bk;  odim = 64; c = t - 64;  cls = 1; ofs = 64; }
    else if (t < 192) { W = Wv;  bias = bv;  odim = 64; c = t - 128; cls = 2; ofs = 128; }
    else if (t < 240) { W = Wqp; bias = bqp; odim = 48; c = t - 192; cls = 3; ofs = 192; }
    else if (t < 288) { W = Wkp; bias = bkp; odim = 48; c = t - 240; cls = 4; ofs = 240; }
    else              { W = Wvp; bias = bvp; odim = 48; c = t - 288; cls = 5; ofs = 288; }
    const float bb = ldm(bias, c, mode);
    float a0 = bb, a1 = bb, a2 = bb, a3 = bb;
    if (mode) {
      const float* Wf = (const float*)W;
      #pragma unroll 8
      for (int f = 0; f < 64; ++f) {
        const float wf = Wf[(size_t)f * odim + c];
        const float4 fv = *(const float4*)(sfT + f * 4);
        a0 = fmaf(fv.x, wf, a0); a1 = fmaf(fv.y, wf, a1);
        a2 = fmaf(fv.z, wf, a2); a3 = fmaf(fv.w, wf, a3);
      }
    } else {
      const bf16* Wb = (const bf16*)W;
      #pragma unroll 8
      for (int f = 0; f < 64; ++f) {
        const float wf = b2f(Wb[(size_t)f * odim + c]);
        const float4 fv = *(const float4*)(sfT + f * 4);
        a0 = fmaf(fv.x, wf, a0); a1 = fmaf(fv.y, wf, a1);
        a2 = fmaf(fv.z, wf, a2); a3 = fmaf(fv.w, wf, a3);
      }
    }
    float av[4] = {a0, a1, a2, a3};
    #pragma unroll
    for (int rr = 0; rr < 4; ++rr) {
      float acc = av[rr];
      if (cls >= 3) {
        acc += ldm(coords, (size_t)(row0 + rr) * 3 + (c % 3), mode);
        if (cls == 3 || cls == 4) acc -= CENTER;   // center qp,kp (shift-inv)
      }
      spro[rr][ofs + c] = acc;
    }
  }
  __syncthreads();

  if (t < 384) {
    const bool isq = (t < 192);
    const int per = isq ? t : t - 192;
    const int h = per / 48, w = per - h * 48;
    const float wl = softplus_f(ldm(w_l, h, mode)) * 0.25f;
    const float wc = softplus_f(ldm(w_c, h, mode));
    uint32* tab = (uint32*)(ws + (isq ? QT_OFF : KT_OFF));
    #pragma unroll 1
    for (int rr = 0; rr < 4; ++rr) {
      const int row = row0 + rr, i = row & 2047;
      float cc[3];
      cc[0] = ldm(coords, (size_t)row * 3 + 0, mode) - CENTER;
      cc[1] = ldm(coords, (size_t)row * 3 + 1, mode) - CENTER;
      cc[2] = ldm(coords, (size_t)row * 3 + 2, mode) - CENTER;
      const float* sp = spro[rr];
      float a0, a1;
      if (isq) { a0 = qslot(h, 2 * w, sp, cc, wl, wc);
                 a1 = qslot(h, 2 * w + 1, sp, cc, wl, wc); }
      else     { a0 = kslot(h, 2 * w, sp, cc, wc);
                 a1 = kslot(h, 2 * w + 1, sp, cc, wc); }
      tab[((size_t)(b * 4 + h) * NN + i) * 48 + w] = pk2(a0, a1);
    }
  } else if (t < 496) {
    const int tt = t - 384;
    const int h = tt / 28, d = tt - h * 28;
    unsigned short* VTu = (unsigned short*)(ws + VT_OFF);
    #pragma unroll 1
    for (int rr = 0; rr < 4; ++rr) {
      const int row = row0 + rr, i = row & 2047;
      const float val = (d < 16) ? spro[rr][128 + h * 16 + d]
                                 : spro[rr][288 + h * 12 + (d - 16)];
      VTu[((size_t)((b * 4 + h) * 28 + d)) * NN + i] = f2bu(val);
    }
  }
}

// ---------------------------------------------------------------------------
// Kernel B: MFMA flash attention — round-16 structure with the d2/bias
// epilogue folded into the MFMAs: sCS buffer, CQ/SB staging role, and the
// 7-op per-r mask math are all GONE. Per r: s = (Cd<-50) ? -1e30 : Cs.
// grid (jc=4, it=16, bh=8), 512 threads.
// ---------------------------------------------------------------------------
__global__ __launch_bounds__(512) void attn_kernel(
    const uint32* __restrict__ QTg, const uint32* __restrict__ KTg,
    const uint32* __restrict__ VTg, float* __restrict__ parb)
{
  const int tid = threadIdx.x;
  const int lane = tid & 63;
  const int li = lane & 15, g = lane >> 4;
  const int jc = blockIdx.x;        // 0..3   (512 j)
  const int it = blockIdx.y;        // 0..15  (128 i)
  const int bh = blockIdx.z;        // 0..7
  const int iloc = it * 128 + (tid >> 6) * 16 + li;
  const int j0base = jc * 512;

  const uint32* qrow = QTg + ((size_t)bh * NN + iloc) * 48;
  const bf16x8 B1 = *(const bf16x8*)(qrow + 4 * g);
  const bf16x8 B2 = *(const bf16x8*)(qrow + 16 + 4 * g);
  const bf16x8 B3 = *(const bf16x8*)(qrow + 32 + 4 * g);

  float m = -1e9f, l = 0.f;
  f32x4 acc0 = {0.f, 0.f, 0.f, 0.f};
  f32x4 acc1 = {0.f, 0.f, 0.f, 0.f};

  __shared__ uint32 sKT[2][32 * 52];   // [buf][32 j][104 bf16] padded rows
  __shared__ uint32 sVT[2][32 * 20];   // [buf][32 d][40 bf16], sigma-permuted

  if (tid < 80) { sVT[0][560 + tid] = 0; sVT[1][560 + tid] = 0; }

  const float4* KT4 = (const float4*)(KTg + ((size_t)bh * NN + j0base) * 48);
  const float4* VT4 = (const float4*)VTg;
  const size_t vbase = (size_t)(bh * 28) * 256 + (j0base >> 3);

  float4 kreg = {0.f, 0.f, 0.f, 0.f};
  float4 vreg = {0.f, 0.f, 0.f, 0.f};
  const int kj = tid / 12, kq = tid - kj * 12;     // tid<384 role
  const int vd = tid >> 2, vq = tid & 3;           // tid<112 role
  const int vA = (vq < 2) ? (8 * vq) : (8 * vq - 14);  // sigma chunk offsets

  auto issue = [&](int jt) {
    if (tid < 384) kreg = KT4[(size_t)jt * 384 + kj * 12 + kq];
    if (tid < 112) vreg = VT4[vbase + (size_t)vd * 256 + jt * 4 + vq];
  };
  auto wr = [&](int bsel) {
    if (tid < 384) *(float4*)(sKT[bsel] + kj * 52 + kq * 4) = kreg;
    if (tid < 112) {
      *(float2*)(sVT[bsel] + vd * 20 + vA)     = make_float2(vreg.x, vreg.y);
      *(float2*)(sVT[bsel] + vd * 20 + vA + 4) = make_float2(vreg.z, vreg.w);
    }
  };

  issue(0);
  wr(0);
  issue(1);

  #pragma unroll 1
  for (int jt = 0; jt < 16; ++jt) {
    const int cur = jt & 1;
    __syncthreads();                  // buf[cur] ready; reads of buf[cur^1] done
    if (jt + 1 < 16) wr(cur ^ 1);     // stage tile jt+1
    if (jt + 2 < 16) issue(jt + 2);   // prefetch tile jt+2 (spans full compute)

    float s[8];
    const f32x4 z = {0.f, 0.f, 0.f, 0.f};
    __builtin_amdgcn_s_setprio(1);
    #pragma unroll
    for (int h2 = 0; h2 < 2; ++h2) {
      const uint32* arow = sKT[cur] + (h2 * 16 + li) * 52;
      const bf16x8 A1 = *(const bf16x8*)(arow + 4 * g);
      const bf16x8 A2 = *(const bf16x8*)(arow + 16 + 4 * g);
      const bf16x8 A3 = *(const bf16x8*)(arow + 32 + 4 * g);
      f32x4 Cs = __builtin_amdgcn_mfma_f32_16x16x32_bf16(A1, B1, z, 0, 0, 0);
      Cs = __builtin_amdgcn_mfma_f32_16x16x32_bf16(A2, B2, Cs, 0, 0, 0);
      const f32x4 Cd = __builtin_amdgcn_mfma_f32_16x16x32_bf16(A3, B3, z, 0, 0, 0);
      #pragma unroll
      for (int r = 0; r < 4; ++r)
        s[h2 * 4 + r] = (Cd[r] < -50.f) ? -1e30f : Cs[r];
    }
    __builtin_amdgcn_s_setprio(0);

    float smax = fmaxf(fmaxf(fmaxf(s[0], s[1]), fmaxf(s[2], s[3])),
                       fmaxf(fmaxf(s[4], s[5]), fmaxf(s[6], s[7])));
    smax = fmaxf(smax, __shfl_xor(smax, 16));
    smax = fmaxf(smax, __shfl_xor(smax, 32));
    const float mnew = fmaxf(m, smax);
    const float alpha = __expf(m - mnew);
    m = mnew;
    l *= alpha; acc0 *= alpha; acc1 *= alpha;
    float p[8];
    #pragma unroll
    for (int k = 0; k < 8; ++k) p[k] = __expf(s[k] - m);
    l += ((p[0] + p[1]) + (p[2] + p[3])) + ((p[4] + p[5]) + (p[6] + p[7]));

    // PV B-operand built entirely in-register (sigma-matched V staging)
    union { uint32 u[4]; bf16x8 v; } bp;
    bp.u[0] = pk2(p[0], p[1]); bp.u[1] = pk2(p[2], p[3]);
    bp.u[2] = pk2(p[4], p[5]); bp.u[3] = pk2(p[6], p[7]);

    const bf16x8 Av0 = *(const bf16x8*)(sVT[cur] + li * 20 + 4 * g);
    const bf16x8 Av1 = *(const bf16x8*)(sVT[cur] + (16 + li) * 20 + 4 * g);
    __builtin_amdgcn_s_setprio(1);
    acc0 = __builtin_amdgcn_mfma_f32_16x16x32_bf16(Av0, bp.v, acc0, 0, 0, 0);
    acc1 = __builtin_amdgcn_mfma_f32_16x16x32_bf16(Av1, bp.v, acc1, 0, 0, 0);
    __builtin_amdgcn_s_setprio(0);
  }

  l += __shfl_xor(l, 16);
  l += __shfl_xor(l, 32);

  float* rec = parb + ((size_t)(bh * 4 + jc) * NN + iloc) * 16;
  rec[0] = m; rec[1] = l;                    // 4 lanes write same values
  uint32* ru = (uint32*)(rec + 2);
  ru[2 * g]     = pk2(acc0[0], acc0[1]);     // slot s holds acc[2s],acc[2s+1]
  ru[2 * g + 1] = pk2(acc0[2], acc0[3]);
  if (g < 3) {
    ru[8 + 2 * g]     = pk2(acc1[0], acc1[1]);
    ru[8 + 2 * g + 1] = pk2(acc1[2], acc1[3]);
  }
}

// ---------------------------------------------------------------------------
// Kernel C: fused combine + output GEMM (verbatim from passing rounds 14/16).
// ---------------------------------------------------------------------------
__global__ __launch_bounds__(256) void out_kernel(
    const float* __restrict__ parb, const void* Wo, const void* bo,
    const unsigned short* __restrict__ ufeat, void* outp)
{
  const int t = threadIdx.x;
  const int blk = blockIdx.x;
  __shared__ int scnt;
  __shared__ float si[4 * 112];
  __shared__ float sM[16], sIL[16];

  if (t == 0) scnt = 0;
  __syncthreads();
  {
    const unsigned e = (ufeat[t] >> 7) & 0xFFu;
    const unsigned long long bl = __ballot(e >= 0xC0u);
    if ((t & 63) == 0) atomicAdd(&scnt, (int)__popcll(bl));
  }
  __syncthreads();
  const int mode = (scnt > 8) ? 1 : 0;

  if (t < 16) {
    const int lr = t >> 2, h = t & 3;
    const int row = blk * 4 + lr, b = row >> 11, i = row & 2047;
    const int bh = b * 4 + h;
    const float* base = parb + ((size_t)(bh * 4) * NN + i) * 16;
    float M = -1e9f;
    #pragma unroll
    for (int c = 0; c < 4; ++c) M = fmaxf(M, base[(size_t)c * NN * 16]);
    float L = 0.f;
    #pragma unroll
    for (int c = 0; c < 4; ++c) {
      const float* r = base + (size_t)c * NN * 16;
      L = fmaf(r[1], __expf(r[0] - M), L);
    }
    sM[t] = M; sIL[t] = 1.f / L;
  }
  __syncthreads();

  if (t < 224) {
    const int u = t / 14, pr = t - u * 14;   // u: (lr,h) 0..15, pr: pair 0..13
    const int lr = u >> 2, h = u & 3;
    const int row = blk * 4 + lr, b = row >> 11, i = row & 2047;
    const int bh = b * 4 + h;
    const float* base = parb + ((size_t)(bh * 4) * NN + i) * 16;
    const float M = sM[u], iL = sIL[u];
    float o0 = 0.f, o1 = 0.f;
    #pragma unroll
    for (int c = 0; c < 4; ++c) {
      const float* r = base + (size_t)c * NN * 16;
      const float wgt = __expf(r[0] - M);
      const float2 f = upk2(((const unsigned*)(r + 2))[pr]);
      o0 = fmaf(f.x, wgt, o0); o1 = fmaf(f.y, wgt, o1);
    }
    const int d = 2 * pr;
    const int col = (d < 16) ? (h * 16 + d) : (64 + h * 12 + (d - 16));
    si[lr * 112 + col]     = o0 * iL;
    si[lr * 112 + col + 1] = o1 * iL;
  }
  __syncthreads();

  const int lr = t >> 6, c = t & 63;
  float acc = mode ? ((const float*)bo)[c] : b2f(((const bf16*)bo)[c]);
  if (mode) {
    const float* Wf = (const float*)Wo;
    #pragma unroll 16
    for (int kk = 0; kk < 112; ++kk)
      acc = fmaf(si[lr * 112 + kk], Wf[(size_t)kk * 64 + c], acc);
  } else {
    const bf16* Wb = (const bf16*)Wo;
    #pragma unroll 16
    for (int kk = 0; kk < 112; ++kk)
      acc = fmaf(si[lr * 112 + kk], b2f(Wb[(size_t)kk * 64 + c]), acc);
  }
  const size_t oi = (size_t)(blk * 4 + lr) * 64 + c;
  if (mode) ((float*)outp)[oi] = acc;
  else      ((bf16*)outp)[oi] = __float2bfloat16(acc);
}

extern "C" void kernel_launch(void* const* d_in, const int* in_sizes, int n_in,
                              void* d_out, int out_size, void* d_ws, size_t ws_size,
                              hipStream_t stream)
{
  float* ws = (float*)d_ws;

  proj_kernel<<<BB * NN / 4, 512, 0, stream>>>(d_in[0], d_in[1], d_in[2], d_in[3],
      d_in[4], d_in[5], d_in[6], d_in[7], d_in[8], d_in[9], d_in[10], d_in[11],
      d_in[12], d_in[13], d_in[16], d_in[17], ws);

  attn_kernel<<<dim3(4, 16, 8), 512, 0, stream>>>(
      (const uint32*)(ws + QT_OFF), (const uint32*)(ws + KT_OFF),
      (const uint32*)(ws + VT_OFF), ws + PAR_OFF);

  out_kernel<<<(BB * NN) / 4, 256, 0, stream>>>(
      ws + PAR_OFF, d_in[14], d_in[15], (const unsigned short*)d_in[0], d_out);
}